// Round 1
// 2391.840 us; speedup vs baseline: 1.0480x; 1.0480x over previous
//
#include <hip/hip_runtime.h>
#include <hip/hip_bf16.h>
#include <cstdint>
#include <cstddef>

#define B_ 128
#define T_ 256
#define H_ 1024
#define V_ 2048

using short8 = __attribute__((ext_vector_type(8))) short;
using f32x4  = __attribute__((ext_vector_type(4))) float;

// ---------- helpers ----------
__device__ __forceinline__ unsigned short f2bf(float f) {
  unsigned u = __builtin_bit_cast(unsigned, f);
  u += 0x7FFFu + ((u >> 16) & 1u);   // RNE
  return (unsigned short)(u >> 16);
}
__device__ __forceinline__ float bf2f(unsigned short h) {
  return __builtin_bit_cast(float, (unsigned)h << 16);
}

typedef __attribute__((address_space(3))) void       lds_void;
typedef __attribute__((address_space(1))) const void gbl_void;

__device__ __forceinline__ void async16(const void* g, void* l) {
  __builtin_amdgcn_global_load_lds((gbl_void*)g, (lds_void*)l, 16, 0, 0);
}

// Cross-XCD h exchange via agent-scope RELAXED atomics: these compile to
// sc0/sc1-annotated global ops that write-through / read-through at the LLC
// (the coherence point). No buffer_wbl2 of dirty data, and NO acquire-side
// buffer_inv — L2 keeps Wx/Wh/inputs resident across all 256 steps.
__device__ __forceinline__ void st_bf16_agent(unsigned short* p, unsigned short v) {
  __hip_atomic_store(p, v, __ATOMIC_RELAXED, __HIP_MEMORY_SCOPE_AGENT);
}
__device__ __forceinline__ unsigned long long ld_u64_agent(const unsigned short* p) {
  return __hip_atomic_load((const unsigned long long*)p,
                           __ATOMIC_RELAXED, __HIP_MEMORY_SCOPE_AGENT);
}

// Per-group flag barrier. Producer side: all h-stores are sc1 write-through;
// __syncthreads drains vmcnt; the flag store keeps RELEASE semantics purely so
// the compiler emits wbl2 (empty — nothing dirty) + vmcnt(0) to drain the L2
// write-through queue before the flag becomes visible. Consumer side: relaxed
// poll, NO acquire fence — all cross-block data loads are sc1 (LLC-direct).
__device__ __forceinline__ void flag_barrier(unsigned* fl, int s, unsigned epoch,
                                             int wave, int lane) {
  __syncthreads();   // all waves' h-stores drained (compiler emits vmcnt(0))
  if (threadIdx.x == 0)
    __hip_atomic_store(fl + s * 32, epoch, __ATOMIC_RELEASE, __HIP_MEMORY_SCOPE_AGENT);
  if (wave == 0) {
    unsigned f;
    do {
      f = __hip_atomic_load(fl + (lane & 31) * 32, __ATOMIC_RELAXED, __HIP_MEMORY_SCOPE_AGENT);
    } while (__ballot(f >= epoch) != ~0ull);
    // no fence: data path is agent-scope (sc1) atomics end-to-end
  }
  __syncthreads();
}

// ---------- kernel 1: Wd (fp32 [H][V]) -> WdT (bf16 [V][H]) ----------
__global__ void wd_transpose(const float* __restrict__ Wd, unsigned short* __restrict__ WdT) {
  __shared__ float tile[64][65];
  const int k0 = blockIdx.x * 64;
  const int n0 = blockIdx.y * 64;
  const int c = threadIdx.x & 63, r4 = threadIdx.x >> 6;
#pragma unroll
  for (int i = 0; i < 16; ++i) {
    int r = i * 4 + r4;
    tile[r][c] = Wd[(size_t)(k0 + r) * V_ + n0 + c];
  }
  __syncthreads();
#pragma unroll
  for (int i = 0; i < 16; ++i) {
    int n = i * 4 + r4;
    WdT[(size_t)(n0 + n) * H_ + k0 + c] = f2bf(tile[c][n]);
  }
}

// ---------- kernel 2: persistent recurrence ----------
// Grid: 256 blocks x 256 threads. Block (g = blockIdx&7, s = blockIdx>>3)
// owns batch rows [16g,16g+16) x hidden cols [32s,32s+32).
// Wh slice (hi/lo bf16) lives in VGPRs; 4 waves split K=1024.
__global__ __launch_bounds__(256, 1) void rnn_recur(
    const int* __restrict__ inputs, const float* __restrict__ state,
    const float* __restrict__ Wx, const float* __restrict__ Wh,
    const float* __restrict__ bias, unsigned short* __restrict__ Yb,
    float* __restrict__ hfinal, unsigned int* __restrict__ flags)
{
  const int tid  = threadIdx.x;
  const int wave = tid >> 6, lane = tid & 63;
  const int g    = blockIdx.x & 7;
  const int s    = blockIdx.x >> 3;
  const int c0   = s * 32;
  const int row0 = g * 16;

  __shared__ float stage[256 * 32];   // 32KB staging for Wh slice (one K-quarter)
  __shared__ float red[4][16][32];    // 8KB cross-wave reduction

  short8 Bf[8][2][2];                 // [k-chunk][col-tile][hi/lo] -> 128 VGPRs

  // ---- prologue: build Wh B-fragments (hi/lo bf16) ----
  for (int p = 0; p < 4; ++p) {
    for (int it = 0; it < 32; ++it) {
      int kk = it * 8 + (tid >> 5);
      stage[kk * 32 + (tid & 31)] = Wh[(size_t)(p * 256 + kk) * H_ + c0 + (tid & 31)];
    }
    __syncthreads();
    if (wave == p) {
#pragma unroll
      for (int ch = 0; ch < 8; ++ch) {
#pragma unroll
        for (int ct = 0; ct < 2; ++ct) {
          short8 hi, lo;
#pragma unroll
          for (int j = 0; j < 8; ++j) {
            int kk = ch * 32 + ((lane >> 4) * 8) + j;
            float f = stage[kk * 32 + ct * 16 + (lane & 15)];
            unsigned short h16 = f2bf(f);
            hi[j] = (short)h16;
            lo[j] = (short)f2bf(f - bf2f(h16));
          }
          Bf[ch][ct][0] = hi;
          Bf[ch][ct][1] = lo;
        }
      }
    }
    __syncthreads();
  }

  // Yb[0] = bf16(state) for this block's tile (agent-scope, LLC-visible)
  for (int i = tid; i < 512; i += 256) {
    int r = i >> 5, c = i & 31;
    st_bf16_agent(Yb + (size_t)(row0 + r) * H_ + c0 + c,
                  f2bf(state[(size_t)(row0 + r) * H_ + c0 + c]));
  }

  unsigned int* fl = flags + g * 32 * 32;   // 32 flags x 128B spacing per group

  const int r0    = tid >> 5;                     // 0..7
  const int cc    = tid & 31;
  const int arow  = row0 + (lane & 15);
  const int kbase = wave * 256 + ((lane >> 4) * 8);

  const float bv0 = bias[c0 + cc];                // loop-invariant

  // prefetch embedding for t=0 (independent of barrier)
  int   tk0 = inputs[(row0 + r0) * T_ + 0];
  int   tk1 = inputs[(row0 + 8 + r0) * T_ + 0];
  float e0  = Wx[(size_t)tk0 * H_ + c0 + cc];
  float e1  = Wx[(size_t)tk1 * H_ + c0 + cc];

  flag_barrier(fl, s, 1u, wave, lane);            // publish state tile (epoch 1)

  for (int t = 0; t < T_; ++t) {
    // A fragments: h_t rows via agent-scope (sc1) loads — read the LLC directly
    const unsigned short* hp = Yb + (size_t)t * (B_ * H_) + (size_t)arow * H_ + kbase;
    short8 A[8];
#pragma unroll
    for (int ch = 0; ch < 8; ++ch) {
      union { unsigned long long q[2]; short8 v; } u;
      u.q[0] = ld_u64_agent(hp + ch * 32);
      u.q[1] = ld_u64_agent(hp + ch * 32 + 4);
      A[ch] = u.v;
    }

    f32x4 acc0 = {0.f, 0.f, 0.f, 0.f}, acc1 = {0.f, 0.f, 0.f, 0.f};
#pragma unroll
    for (int ch = 0; ch < 8; ++ch) {
      acc0 = __builtin_amdgcn_mfma_f32_16x16x32_bf16(A[ch], Bf[ch][0][0], acc0, 0, 0, 0);
      acc1 = __builtin_amdgcn_mfma_f32_16x16x32_bf16(A[ch], Bf[ch][1][0], acc1, 0, 0, 0);
      acc0 = __builtin_amdgcn_mfma_f32_16x16x32_bf16(A[ch], Bf[ch][0][1], acc0, 0, 0, 0);
      acc1 = __builtin_amdgcn_mfma_f32_16x16x32_bf16(A[ch], Bf[ch][1][1], acc1, 0, 0, 0);
    }

    // cross-wave K reduction via LDS
#pragma unroll
    for (int r = 0; r < 4; ++r) {
      red[wave][(lane >> 4) * 4 + r][lane & 15]        = acc0[r];
      red[wave][(lane >> 4) * 4 + r][16 + (lane & 15)] = acc1[r];
    }
    __syncthreads();

    float v0 = red[0][r0][cc] + red[1][r0][cc] + red[2][r0][cc] + red[3][r0][cc] + e0 + bv0;
    float v1 = red[0][8 + r0][cc] + red[1][8 + r0][cc] + red[2][8 + r0][cc] + red[3][8 + r0][cc]
             + e1 + bv0;
    float h0 = tanhf(v0), h1 = tanhf(v1);

    size_t obase = (size_t)(t + 1) * (B_ * H_);
    st_bf16_agent(Yb + obase + (size_t)(row0 + r0) * H_ + c0 + cc,     f2bf(h0));
    st_bf16_agent(Yb + obase + (size_t)(row0 + 8 + r0) * H_ + c0 + cc, f2bf(h1));

    if (t == T_ - 1) {
      hfinal[(size_t)(row0 + r0) * H_ + c0 + cc]     = h0;
      hfinal[(size_t)(row0 + 8 + r0) * H_ + c0 + cc] = h1;
    } else {
      // prefetch next step's embedding BEFORE the wait (hides under the spin)
      tk0 = inputs[(row0 + r0) * T_ + t + 1];
      tk1 = inputs[(row0 + 8 + r0) * T_ + t + 1];
      e0  = Wx[(size_t)tk0 * H_ + c0 + cc];
      e1  = Wx[(size_t)tk1 * H_ + c0 + cc];
      flag_barrier(fl, s, (unsigned)(t + 2), wave, lane);
    }
  }
}

// ---------- kernel 3: projection GEMM ----------
__global__ __launch_bounds__(256, 2) void proj_gemm(
    const unsigned short* __restrict__ A,   // Yb + B*H
    const unsigned short* __restrict__ Bt,  // [2048][1024] bf16
    const float* __restrict__ bd, float* __restrict__ out)
{
  const int tid = threadIdx.x;
  const int wave = tid >> 6, lane = tid & 63;
  const int wm = wave >> 1, wn = wave & 1;
  const int m0 = blockIdx.y * 128, n0 = blockIdx.x * 128;

  __shared__ unsigned short As[128 * 32];
  __shared__ unsigned short Bs[128 * 32];

  f32x4 acc[4][4];
#pragma unroll
  for (int i = 0; i < 4; ++i)
#pragma unroll
    for (int j = 0; j < 4; ++j)
      acc[i][j] = (f32x4){0.f, 0.f, 0.f, 0.f};

  const int lrow = tid >> 2;
  const int lcol = (tid & 3) * 16;

  for (int k0 = 0; k0 < H_; k0 += 32) {
    __syncthreads();
    async16((const char*)(A  + (size_t)(m0 + lrow)      * H_ + k0) + lcol, (char*)As + tid * 16);
    async16((const char*)(A  + (size_t)(m0 + 64 + lrow) * H_ + k0) + lcol, (char*)As + 4096 + tid * 16);
    async16((const char*)(Bt + (size_t)(n0 + lrow)      * H_ + k0) + lcol, (char*)Bs + tid * 16);
    async16((const char*)(Bt + (size_t)(n0 + 64 + lrow) * H_ + k0) + lcol, (char*)Bs + 4096 + tid * 16);
    __syncthreads();

    short8 af[4], bf[4];
#pragma unroll
    for (int i = 0; i < 4; ++i) {
      af[i] = *(const short8*)(As + (wm * 64 + i * 16 + (lane & 15)) * 32 + (lane >> 4) * 8);
      bf[i] = *(const short8*)(Bs + (wn * 64 + i * 16 + (lane & 15)) * 32 + (lane >> 4) * 8);
    }
#pragma unroll
    for (int i = 0; i < 4; ++i)
#pragma unroll
      for (int j = 0; j < 4; ++j)
        acc[i][j] = __builtin_amdgcn_mfma_f32_16x16x32_bf16(af[i], bf[j], acc[i][j], 0, 0, 0);
  }

#pragma unroll
  for (int i = 0; i < 4; ++i) {
#pragma unroll
    for (int j = 0; j < 4; ++j) {
      int n = n0 + wn * 64 + j * 16 + (lane & 15);
      float bv = bd[n];
#pragma unroll
      for (int r = 0; r < 4; ++r) {
        int m = m0 + wm * 64 + i * 16 + (lane >> 4) * 4 + r;
        out[(size_t)m * V_ + n] = acc[i][j][r] + bv;
      }
    }
  }
}

// ---------- workspace layout ----------
static constexpr size_t YB_BYTES  = (size_t)(T_ + 1) * B_ * H_ * 2;  // 67,371,008
static constexpr size_t WDT_OFF   = YB_BYTES;
static constexpr size_t WDT_BYTES = (size_t)V_ * H_ * 2;             // 4,194,304
static constexpr size_t BAR_OFF   = WDT_OFF + WDT_BYTES;
static constexpr size_t BAR_BYTES = 8 * 32 * 128;                    // 32 KB flag area

extern "C" void kernel_launch(void* const* d_in, const int* in_sizes, int n_in,
                              void* d_out, int out_size, void* d_ws, size_t ws_size,
                              hipStream_t stream) {
  const int*   inputs = (const int*)d_in[0];
  const float* state  = (const float*)d_in[1];
  const float* Wx     = (const float*)d_in[2];
  const float* Wh     = (const float*)d_in[3];
  const float* b      = (const float*)d_in[4];
  const float* Wd     = (const float*)d_in[5];
  const float* bd     = (const float*)d_in[6];

  float* out    = (float*)d_out;
  float* hfinal = out + (size_t)T_ * B_ * V_;

  unsigned short* Yb    = (unsigned short*)d_ws;
  unsigned short* WdT   = (unsigned short*)((char*)d_ws + WDT_OFF);
  unsigned int*   flags = (unsigned int*)((char*)d_ws + BAR_OFF);

  hipMemsetAsync(flags, 0, BAR_BYTES, stream);   // ws is 0xAA-poisoned each call
  wd_transpose<<<dim3(16, 32), 256, 0, stream>>>(Wd, WdT);
  rnn_recur<<<256, 256, 0, stream>>>(inputs, state, Wx, Wh, b, Yb, hfinal, flags);
  proj_gemm<<<dim3(16, 256), 256, 0, stream>>>(Yb + (size_t)B_ * H_, WdT, bd, out);
}

// Round 4
// 2054.752 us; speedup vs baseline: 1.2199x; 1.1641x over previous
//
#include <hip/hip_runtime.h>
#include <hip/hip_bf16.h>
#include <cstdint>
#include <cstddef>

#define B_ 128
#define T_ 256
#define H_ 1024
#define V_ 2048

using short8 = __attribute__((ext_vector_type(8))) short;
using f32x4  = __attribute__((ext_vector_type(4))) float;

// ---------- helpers ----------
__device__ __forceinline__ unsigned short f2bf(float f) {
  unsigned u = __builtin_bit_cast(unsigned, f);
  u += 0x7FFFu + ((u >> 16) & 1u);   // RNE
  return (unsigned short)(u >> 16);
}
__device__ __forceinline__ float bf2f(unsigned short h) {
  return __builtin_bit_cast(float, (unsigned)h << 16);
}

typedef __attribute__((address_space(3))) void       lds_void;
typedef __attribute__((address_space(1))) const void gbl_void;

__device__ __forceinline__ void async16(const void* g, void* l) {
  __builtin_amdgcn_global_load_lds((gbl_void*)g, (lds_void*)l, 16, 0, 0);
}

// ---------- agent-scope (LLC) primitives — round-1 known-good ----------
__device__ __forceinline__ void st_bf16_agent(unsigned short* p, unsigned short v) {
  __hip_atomic_store(p, v, __ATOMIC_RELAXED, __HIP_MEMORY_SCOPE_AGENT);
}
__device__ __forceinline__ unsigned long long ld_u64_agent(const unsigned short* p) {
  return __hip_atomic_load((const unsigned long long*)p,
                           __ATOMIC_RELAXED, __HIP_MEMORY_SCOPE_AGENT);
}
// Shared by BOTH protocols (proven in rounds 0/1). Producer h-stores are
// drained (vmcnt(0)) by __syncthreads before the release flag store.
__device__ __forceinline__ void flag_barrier(unsigned* fl, int s, unsigned epoch,
                                             int wave, int lane) {
  __syncthreads();
  if (threadIdx.x == 0)
    __hip_atomic_store(fl + s * 32, epoch, __ATOMIC_RELEASE, __HIP_MEMORY_SCOPE_AGENT);
  if (wave == 0) {
    unsigned f;
    do {
      f = __hip_atomic_load(fl + (lane & 31) * 32, __ATOMIC_RELAXED, __HIP_MEMORY_SCOPE_AGENT);
    } while (__ballot(f >= epoch) != ~0ull);
  }
  __syncthreads();
}

// ---------- kernel 1: Wd (fp32 [H][V]) -> WdT (bf16 [V][H]) ----------
__global__ void wd_transpose(const float* __restrict__ Wd, unsigned short* __restrict__ WdT) {
  __shared__ float tile[64][65];
  const int k0 = blockIdx.x * 64;
  const int n0 = blockIdx.y * 64;
  const int c = threadIdx.x & 63, r4 = threadIdx.x >> 6;
#pragma unroll
  for (int i = 0; i < 16; ++i) {
    int r = i * 4 + r4;
    tile[r][c] = Wd[(size_t)(k0 + r) * V_ + n0 + c];
  }
  __syncthreads();
#pragma unroll
  for (int i = 0; i < 16; ++i) {
    int n = i * 4 + r4;
    WdT[(size_t)(n0 + n) * H_ + k0 + c] = f2bf(tile[c][n]);
  }
}

// ---------- the T-step recurrence loop, data-path-templated ----------
// FAST (same-XCD verified): h-stores are PLAIN (write-through L1 -> shared L2);
// A-loads are PLAIN (epoch-fresh addresses -> guaranteed L1 miss -> L2 hit).
// SLOW (cross-XCD): sc1 agent atomics end-to-end (round-1 protocol).
// Flag barrier is the SAME sc1 protocol for both.
template<bool FAST>
__device__ __forceinline__ void run_T_loop(
    const int* __restrict__ inputs, const float* __restrict__ Wx,
    unsigned short* __restrict__ Yb, float* __restrict__ hfinal,
    unsigned* fl, int s, int wave, int lane,
    const short8 (&Bf)[8][2][2], float (*red)[16][32],
    int r0, int cc, int arow, int kbase, float bv0, int row0, int c0)
{
  // prefetch embedding for t=0 (independent of barrier)
  int   tk0 = inputs[(row0 + r0) * T_ + 0];
  int   tk1 = inputs[(row0 + 8 + r0) * T_ + 0];
  float e0  = Wx[(size_t)tk0 * H_ + c0 + cc];
  float e1  = Wx[(size_t)tk1 * H_ + c0 + cc];

  flag_barrier(fl, s, 1u, wave, lane);   // publish state tile (epoch 1)

  for (int t = 0; t < T_; ++t) {
    const unsigned short* hp = Yb + (size_t)t * (B_ * H_) + (size_t)arow * H_ + kbase;
    short8 A[8];
    if (FAST) {
#pragma unroll
      for (int ch = 0; ch < 8; ++ch)
        A[ch] = *(const short8*)(hp + ch * 32);
    } else {
#pragma unroll
      for (int ch = 0; ch < 8; ++ch) {
        union { unsigned long long q[2]; short8 v; } u;
        u.q[0] = ld_u64_agent(hp + ch * 32);
        u.q[1] = ld_u64_agent(hp + ch * 32 + 4);
        A[ch] = u.v;
      }
    }

    f32x4 acc0 = {0.f, 0.f, 0.f, 0.f}, acc1 = {0.f, 0.f, 0.f, 0.f};
#pragma unroll
    for (int ch = 0; ch < 8; ++ch) {
      acc0 = __builtin_amdgcn_mfma_f32_16x16x32_bf16(A[ch], Bf[ch][0][0], acc0, 0, 0, 0);
      acc1 = __builtin_amdgcn_mfma_f32_16x16x32_bf16(A[ch], Bf[ch][1][0], acc1, 0, 0, 0);
      acc0 = __builtin_amdgcn_mfma_f32_16x16x32_bf16(A[ch], Bf[ch][0][1], acc0, 0, 0, 0);
      acc1 = __builtin_amdgcn_mfma_f32_16x16x32_bf16(A[ch], Bf[ch][1][1], acc1, 0, 0, 0);
    }

    // cross-wave K reduction via LDS
#pragma unroll
    for (int r = 0; r < 4; ++r) {
      red[wave][(lane >> 4) * 4 + r][lane & 15]        = acc0[r];
      red[wave][(lane >> 4) * 4 + r][16 + (lane & 15)] = acc1[r];
    }
    __syncthreads();

    float v0 = red[0][r0][cc] + red[1][r0][cc] + red[2][r0][cc] + red[3][r0][cc] + e0 + bv0;
    float v1 = red[0][8 + r0][cc] + red[1][8 + r0][cc] + red[2][8 + r0][cc] + red[3][8 + r0][cc]
             + e1 + bv0;
    float h0 = tanhf(v0), h1 = tanhf(v1);

    const size_t obase = (size_t)(t + 1) * (B_ * H_);
    unsigned short* sp0 = Yb + obase + (size_t)(row0 + r0) * H_ + c0 + cc;
    unsigned short* sp1 = Yb + obase + (size_t)(row0 + 8 + r0) * H_ + c0 + cc;
    if (FAST) {
      *sp0 = f2bf(h0);                 // plain: write-through L1 -> shared L2
      *sp1 = f2bf(h1);
    } else {
      st_bf16_agent(sp0, f2bf(h0));
      st_bf16_agent(sp1, f2bf(h1));
    }

    if (t == T_ - 1) {
      hfinal[(size_t)(row0 + r0) * H_ + c0 + cc]     = h0;
      hfinal[(size_t)(row0 + 8 + r0) * H_ + c0 + cc] = h1;
    } else {
      // prefetch next step's embedding BEFORE the wait (hides under the spin)
      tk0 = inputs[(row0 + r0) * T_ + t + 1];
      tk1 = inputs[(row0 + 8 + r0) * T_ + t + 1];
      e0  = Wx[(size_t)tk0 * H_ + c0 + cc];
      e1  = Wx[(size_t)tk1 * H_ + c0 + cc];
      flag_barrier(fl, s, (unsigned)(t + 2), wave, lane);
    }
  }
}

// ---------- kernel 2: persistent recurrence ----------
// Grid: 256 blocks x 256 threads. Block (g = blockIdx&7, s = blockIdx>>3)
// owns batch rows [16g,16g+16) x hidden cols [32s,32s+32).
// If runtime verification shows (a) my group's 32 blocks share one XCC id and
// (b) the neighbor group contains a DIFFERENT id (rules out constant-garbage
// register reads), the h-exchange uses the intra-XCD shared L2 (plain ops);
// otherwise the round-1 LLC protocol.
__global__ __launch_bounds__(256, 1) void rnn_recur(
    const int* __restrict__ inputs, const float* __restrict__ state,
    const float* __restrict__ Wx, const float* __restrict__ Wh,
    const float* __restrict__ bias, unsigned short* __restrict__ Yb,
    float* __restrict__ hfinal, unsigned int* __restrict__ flags)
{
  const int tid  = threadIdx.x;
  const int wave = tid >> 6, lane = tid & 63;
  const int g    = blockIdx.x & 7;
  const int s    = blockIdx.x >> 3;
  const int c0   = s * 32;
  const int row0 = g * 16;

  unsigned* fl = flags + g * 32 * 32;   // 32 slots x 128B per group; flag @+0, xcc id @+64B

  // Read XCC_ID (hwreg id 20, offset 0, width 4) via builtin — no asm parser.
  const unsigned xcc = __builtin_amdgcn_s_getreg(((4 - 1) << 11) | 20);
  if (tid == 0)
    __hip_atomic_store(fl + s * 32 + 16, xcc + 1u, __ATOMIC_RELAXED, __HIP_MEMORY_SCOPE_AGENT);

  __shared__ float stage[256 * 32];   // 32KB staging for Wh slice (one K-quarter)
  __shared__ float red[4][16][32];    // 8KB cross-wave reduction
  __shared__ unsigned same_sh;

  short8 Bf[8][2][2];                 // [k-chunk][col-tile][hi/lo] -> 128 VGPRs

  // ---- prologue: build Wh B-fragments (hi/lo bf16) ----
  for (int p = 0; p < 4; ++p) {
    for (int it = 0; it < 32; ++it) {
      int kk = it * 8 + (tid >> 5);
      stage[kk * 32 + (tid & 31)] = Wh[(size_t)(p * 256 + kk) * H_ + c0 + (tid & 31)];
    }
    __syncthreads();
    if (wave == p) {
#pragma unroll
      for (int ch = 0; ch < 8; ++ch) {
#pragma unroll
        for (int ct = 0; ct < 2; ++ct) {
          short8 hi, lo;
#pragma unroll
          for (int j = 0; j < 8; ++j) {
            int kk = ch * 32 + ((lane >> 4) * 8) + j;
            float f = stage[kk * 32 + ct * 16 + (lane & 15)];
            unsigned short h16 = f2bf(f);
            hi[j] = (short)h16;
            lo[j] = (short)f2bf(f - bf2f(h16));
          }
          Bf[ch][ct][0] = hi;
          Bf[ch][ct][1] = lo;
        }
      }
    }
    __syncthreads();
  }

  // ---- protocol selection: same-XCD within group AND neighbor group differs ----
  // Spins terminate: all 256 blocks are co-resident (proven by rounds 0/1's
  // passing global flag barrier) and publish their id before any spin.
  if (wave == 0) {
    unsigned idv;
    do {
      idv = __hip_atomic_load(fl + (lane & 31) * 32 + 16,
                              __ATOMIC_RELAXED, __HIP_MEMORY_SCOPE_AGENT);
    } while (__ballot(idv != 0u) != ~0ull);
    const bool uniform = (__ballot(idv == xcc + 1u) == ~0ull);

    unsigned* nfl = flags + ((g + 1) & 7) * 32 * 32;
    unsigned ndv;
    do {
      ndv = __hip_atomic_load(nfl + (lane & 31) * 32 + 16,
                              __ATOMIC_RELAXED, __HIP_MEMORY_SCOPE_AGENT);
    } while (__ballot(ndv != 0u) != ~0ull);
    const bool differs = (__ballot(ndv != xcc + 1u) != 0ull);

    if (lane == 0) same_sh = (uniform && differs) ? 1u : 0u;
  }
  __syncthreads();
  const bool fastp = (same_sh != 0u);

  const int r0    = tid >> 5;                     // 0..7
  const int cc    = tid & 31;
  const int arow  = row0 + (lane & 15);
  const int kbase = wave * 256 + ((lane >> 4) * 8);
  const float bv0 = bias[c0 + cc];                // loop-invariant

  // Yb[0] = bf16(state) for this block's tile
  if (fastp) {
    for (int i = tid; i < 512; i += 256) {
      int r = i >> 5, c = i & 31;
      Yb[(size_t)(row0 + r) * H_ + c0 + c] = f2bf(state[(size_t)(row0 + r) * H_ + c0 + c]);
    }
    run_T_loop<true>(inputs, Wx, Yb, hfinal, fl, s, wave, lane, Bf, red,
                     r0, cc, arow, kbase, bv0, row0, c0);
  } else {
    for (int i = tid; i < 512; i += 256) {
      int r = i >> 5, c = i & 31;
      st_bf16_agent(Yb + (size_t)(row0 + r) * H_ + c0 + c,
                    f2bf(state[(size_t)(row0 + r) * H_ + c0 + c]));
    }
    run_T_loop<false>(inputs, Wx, Yb, hfinal, fl, s, wave, lane, Bf, red,
                      r0, cc, arow, kbase, bv0, row0, c0);
  }
}

// ---------- kernel 3: projection GEMM ----------
__global__ __launch_bounds__(256, 2) void proj_gemm(
    const unsigned short* __restrict__ A,   // Yb + B*H
    const unsigned short* __restrict__ Bt,  // [2048][1024] bf16
    const float* __restrict__ bd, float* __restrict__ out)
{
  const int tid = threadIdx.x;
  const int wave = tid >> 6, lane = tid & 63;
  const int wm = wave >> 1, wn = wave & 1;
  const int m0 = blockIdx.y * 128, n0 = blockIdx.x * 128;

  __shared__ unsigned short As[128 * 32];
  __shared__ unsigned short Bs[128 * 32];

  f32x4 acc[4][4];
#pragma unroll
  for (int i = 0; i < 4; ++i)
#pragma unroll
    for (int j = 0; j < 4; ++j)
      acc[i][j] = (f32x4){0.f, 0.f, 0.f, 0.f};

  const int lrow = tid >> 2;
  const int lcol = (tid & 3) * 16;

  for (int k0 = 0; k0 < H_; k0 += 32) {
    __syncthreads();
    async16((const char*)(A  + (size_t)(m0 + lrow)      * H_ + k0) + lcol, (char*)As + tid * 16);
    async16((const char*)(A  + (size_t)(m0 + 64 + lrow) * H_ + k0) + lcol, (char*)As + 4096 + tid * 16);
    async16((const char*)(Bt + (size_t)(n0 + lrow)      * H_ + k0) + lcol, (char*)Bs + tid * 16);
    async16((const char*)(Bt + (size_t)(n0 + 64 + lrow) * H_ + k0) + lcol, (char*)Bs + 4096 + tid * 16);
    __syncthreads();

    short8 af[4], bf[4];
#pragma unroll
    for (int i = 0; i < 4; ++i) {
      af[i] = *(const short8*)(As + (wm * 64 + i * 16 + (lane & 15)) * 32 + (lane >> 4) * 8);
      bf[i] = *(const short8*)(Bs + (wn * 64 + i * 16 + (lane & 15)) * 32 + (lane >> 4) * 8);
    }
#pragma unroll
    for (int i = 0; i < 4; ++i)
#pragma unroll
      for (int j = 0; j < 4; ++j)
        acc[i][j] = __builtin_amdgcn_mfma_f32_16x16x32_bf16(af[i], bf[j], acc[i][j], 0, 0, 0);
  }

#pragma unroll
  for (int i = 0; i < 4; ++i) {
#pragma unroll
    for (int j = 0; j < 4; ++j) {
      int n = n0 + wn * 64 + j * 16 + (lane & 15);
      float bv = bd[n];
#pragma unroll
      for (int r = 0; r < 4; ++r) {
        int m = m0 + wm * 64 + i * 16 + (lane >> 4) * 4 + r;
        out[(size_t)m * V_ + n] = acc[i][j][r] + bv;
      }
    }
  }
}

// ---------- workspace layout ----------
static constexpr size_t YB_BYTES  = (size_t)(T_ + 1) * B_ * H_ * 2;  // 67,371,008
static constexpr size_t WDT_OFF   = YB_BYTES;
static constexpr size_t WDT_BYTES = (size_t)V_ * H_ * 2;             // 4,194,304
static constexpr size_t BAR_OFF   = WDT_OFF + WDT_BYTES;
static constexpr size_t BAR_BYTES = 8 * 32 * 128;                    // 32 KB flag+id area

extern "C" void kernel_launch(void* const* d_in, const int* in_sizes, int n_in,
                              void* d_out, int out_size, void* d_ws, size_t ws_size,
                              hipStream_t stream) {
  const int*   inputs = (const int*)d_in[0];
  const float* state  = (const float*)d_in[1];
  const float* Wx     = (const float*)d_in[2];
  const float* Wh     = (const float*)d_in[3];
  const float* b      = (const float*)d_in[4];
  const float* Wd     = (const float*)d_in[5];
  const float* bd     = (const float*)d_in[6];

  float* out    = (float*)d_out;
  float* hfinal = out + (size_t)T_ * B_ * V_;

  unsigned short* Yb    = (unsigned short*)d_ws;
  unsigned short* WdT   = (unsigned short*)((char*)d_ws + WDT_OFF);
  unsigned int*   flags = (unsigned int*)((char*)d_ws + BAR_OFF);

  hipMemsetAsync(flags, 0, BAR_BYTES, stream);   // ws is 0xAA-poisoned each call
  wd_transpose<<<dim3(16, 32), 256, 0, stream>>>(Wd, WdT);
  rnn_recur<<<256, 256, 0, stream>>>(inputs, state, Wx, Wh, b, Yb, hfinal, flags);
  proj_gemm<<<dim3(16, 256), 256, 0, stream>>>(Yb + (size_t)B_ * H_, WdT, bd, out);
}

// Round 5
// 1420.835 us; speedup vs baseline: 1.7642x; 1.4462x over previous
//
#include <hip/hip_runtime.h>
#include <hip/hip_bf16.h>
#include <cstdint>
#include <cstddef>

#define B_ 128
#define T_ 256
#define H_ 1024
#define V_ 2048

using short8 = __attribute__((ext_vector_type(8))) short;
using f32x4  = __attribute__((ext_vector_type(4))) float;

// ---------- helpers ----------
__device__ __forceinline__ unsigned short f2bf(float f) {
  unsigned u = __builtin_bit_cast(unsigned, f);
  u += 0x7FFFu + ((u >> 16) & 1u);   // RNE
  return (unsigned short)(u >> 16);
}
__device__ __forceinline__ float bf2f(unsigned short h) {
  return __builtin_bit_cast(float, (unsigned)h << 16);
}

typedef __attribute__((address_space(3))) void       lds_void;
typedef __attribute__((address_space(1))) const void gbl_void;

__device__ __forceinline__ void async16(const void* g, void* l) {
  __builtin_amdgcn_global_load_lds((gbl_void*)g, (lds_void*)l, 16, 0, 0);
}

// ---------- agent-scope (LLC) primitives — round-1 known-good (slow path) ----------
__device__ __forceinline__ void st_bf16_agent(unsigned short* p, unsigned short v) {
  __hip_atomic_store(p, v, __ATOMIC_RELAXED, __HIP_MEMORY_SCOPE_AGENT);
}
__device__ __forceinline__ unsigned long long ld_u64_agent(const unsigned short* p) {
  return __hip_atomic_load((const unsigned long long*)p,
                           __ATOMIC_RELAXED, __HIP_MEMORY_SCOPE_AGENT);
}
__device__ __forceinline__ void flag_barrier(unsigned* fl, int s, unsigned epoch,
                                             int wave, int lane) {
  __syncthreads();
  if (threadIdx.x == 0)
    __hip_atomic_store(fl + s * 32, epoch, __ATOMIC_RELEASE, __HIP_MEMORY_SCOPE_AGENT);
  if (wave == 0) {
    unsigned f;
    do {
      f = __hip_atomic_load(fl + (lane & 31) * 32, __ATOMIC_RELAXED, __HIP_MEMORY_SCOPE_AGENT);
    } while (__ballot(f >= epoch) != ~0ull);
  }
  __syncthreads();
}

// ---------- fast-path barrier: single shared counter in the XCD's L2 ----------
// Atomic RMWs execute at the L2 (never L1), and relaxed workgroup-scope RMW
// carries no cache-maintenance ops — no wbl2 flush, no LLC trip. h-stores are
// plain (write-through L1 -> L2) and are ACKED AT L2 by the vmcnt(0) drain
// that __syncthreads emits, so counter-add-after-barrier orders them.
// The poll uses fetch_add of an OPAQUE zero so LLVM cannot canonicalize the
// idempotent RMW into an atomic load (which would be a plain, L1-served load).
__device__ __forceinline__ void counter_barrier(unsigned* cnt, unsigned target) {
  __syncthreads();                      // drains vmcnt -> h-stores committed in L2
  if (threadIdx.x == 0) {
    __hip_atomic_fetch_add(cnt, 1u, __ATOMIC_RELAXED, __HIP_MEMORY_SCOPE_WORKGROUP);
    unsigned z = 0u;
    asm volatile("" : "+v"(z));         // opaque zero (empty asm, no instructions)
    unsigned v;
    do {
      v = __hip_atomic_fetch_add(cnt, z, __ATOMIC_RELAXED, __HIP_MEMORY_SCOPE_WORKGROUP);
    } while (v < target);
  }
  __syncthreads();
}

// ---------- kernel 1: Wd (fp32 [H][V]) -> WdT (bf16 [V][H]) ----------
__global__ void wd_transpose(const float* __restrict__ Wd, unsigned short* __restrict__ WdT) {
  __shared__ float tile[64][65];
  const int k0 = blockIdx.x * 64;
  const int n0 = blockIdx.y * 64;
  const int c = threadIdx.x & 63, r4 = threadIdx.x >> 6;
#pragma unroll
  for (int i = 0; i < 16; ++i) {
    int r = i * 4 + r4;
    tile[r][c] = Wd[(size_t)(k0 + r) * V_ + n0 + c];
  }
  __syncthreads();
#pragma unroll
  for (int i = 0; i < 16; ++i) {
    int n = i * 4 + r4;
    WdT[(size_t)(n0 + n) * H_ + k0 + c] = f2bf(tile[c][n]);
  }
}

// ---------- the T-step recurrence loop, protocol-templated ----------
// FAST (same-XCD verified): plain h-stores/A-loads through the shared L2;
// barrier = counter_barrier (L2-resident atomic counter).
// SLOW (cross-XCD): round-1 sc1 protocol end-to-end.
template<bool FAST>
__device__ __forceinline__ void run_T_loop(
    const int* __restrict__ inputs, const float* __restrict__ Wx,
    unsigned short* __restrict__ Yb, float* __restrict__ hfinal,
    unsigned* fl, unsigned* cnt, int s, int wave, int lane,
    const short8 (&Bf)[8][2][2], float (*red)[16][32],
    int r0, int cc, int arow, int kbase, float bv0, int row0, int c0)
{
  // prefetch embedding for t=0 (independent of barrier)
  int   tk0 = inputs[(row0 + r0) * T_ + 0];
  int   tk1 = inputs[(row0 + 8 + r0) * T_ + 0];
  float e0  = Wx[(size_t)tk0 * H_ + c0 + cc];
  float e1  = Wx[(size_t)tk1 * H_ + c0 + cc];

  if (FAST) counter_barrier(cnt, 32u * 1u);
  else      flag_barrier(fl, s, 1u, wave, lane);   // publish state tile (epoch 1)

  for (int t = 0; t < T_; ++t) {
    const unsigned short* hp = Yb + (size_t)t * (B_ * H_) + (size_t)arow * H_ + kbase;
    short8 A[8];
    if (FAST) {
#pragma unroll
      for (int ch = 0; ch < 8; ++ch)
        A[ch] = *(const short8*)(hp + ch * 32);
    } else {
#pragma unroll
      for (int ch = 0; ch < 8; ++ch) {
        union { unsigned long long q[2]; short8 v; } u;
        u.q[0] = ld_u64_agent(hp + ch * 32);
        u.q[1] = ld_u64_agent(hp + ch * 32 + 4);
        A[ch] = u.v;
      }
    }

    f32x4 acc0 = {0.f, 0.f, 0.f, 0.f}, acc1 = {0.f, 0.f, 0.f, 0.f};
#pragma unroll
    for (int ch = 0; ch < 8; ++ch) {
      acc0 = __builtin_amdgcn_mfma_f32_16x16x32_bf16(A[ch], Bf[ch][0][0], acc0, 0, 0, 0);
      acc1 = __builtin_amdgcn_mfma_f32_16x16x32_bf16(A[ch], Bf[ch][1][0], acc1, 0, 0, 0);
      acc0 = __builtin_amdgcn_mfma_f32_16x16x32_bf16(A[ch], Bf[ch][0][1], acc0, 0, 0, 0);
      acc1 = __builtin_amdgcn_mfma_f32_16x16x32_bf16(A[ch], Bf[ch][1][1], acc1, 0, 0, 0);
    }

    // cross-wave K reduction via LDS
#pragma unroll
    for (int r = 0; r < 4; ++r) {
      red[wave][(lane >> 4) * 4 + r][lane & 15]        = acc0[r];
      red[wave][(lane >> 4) * 4 + r][16 + (lane & 15)] = acc1[r];
    }
    __syncthreads();

    float v0 = red[0][r0][cc] + red[1][r0][cc] + red[2][r0][cc] + red[3][r0][cc] + e0 + bv0;
    float v1 = red[0][8 + r0][cc] + red[1][8 + r0][cc] + red[2][8 + r0][cc] + red[3][8 + r0][cc]
             + e1 + bv0;
    float h0 = tanhf(v0), h1 = tanhf(v1);

    const size_t obase = (size_t)(t + 1) * (B_ * H_);
    unsigned short* sp0 = Yb + obase + (size_t)(row0 + r0) * H_ + c0 + cc;
    unsigned short* sp1 = Yb + obase + (size_t)(row0 + 8 + r0) * H_ + c0 + cc;
    if (FAST) {
      *sp0 = f2bf(h0);                 // plain: write-through L1 -> shared L2
      *sp1 = f2bf(h1);
    } else {
      st_bf16_agent(sp0, f2bf(h0));
      st_bf16_agent(sp1, f2bf(h1));
    }

    if (t == T_ - 1) {
      hfinal[(size_t)(row0 + r0) * H_ + c0 + cc]     = h0;
      hfinal[(size_t)(row0 + 8 + r0) * H_ + c0 + cc] = h1;
    } else {
      // prefetch next step's embedding BEFORE the wait (hides under the spin)
      tk0 = inputs[(row0 + r0) * T_ + t + 1];
      tk1 = inputs[(row0 + 8 + r0) * T_ + t + 1];
      e0  = Wx[(size_t)tk0 * H_ + c0 + cc];
      e1  = Wx[(size_t)tk1 * H_ + c0 + cc];
      if (FAST) counter_barrier(cnt, 32u * (unsigned)(t + 2));
      else      flag_barrier(fl, s, (unsigned)(t + 2), wave, lane);
    }
  }
}

// ---------- kernel 2: persistent recurrence ----------
// Grid: 256 blocks x 256 threads. Block (g = blockIdx&7, s = blockIdx>>3)
// owns batch rows [16g,16g+16) x hidden cols [32s,32s+32).
// If runtime verification shows (a) my group's 32 blocks share one XCC id and
// (b) the neighbor group contains a DIFFERENT id (rules out constant-garbage
// register reads), the h-exchange AND the barrier use the intra-XCD shared L2;
// otherwise the round-1 LLC protocol.
__global__ __launch_bounds__(256, 1) void rnn_recur(
    const int* __restrict__ inputs, const float* __restrict__ state,
    const float* __restrict__ Wx, const float* __restrict__ Wh,
    const float* __restrict__ bias, unsigned short* __restrict__ Yb,
    float* __restrict__ hfinal, unsigned int* __restrict__ flags)
{
  const int tid  = threadIdx.x;
  const int wave = tid >> 6, lane = tid & 63;
  const int g    = blockIdx.x & 7;
  const int s    = blockIdx.x >> 3;
  const int c0   = s * 32;
  const int row0 = g * 16;

  unsigned* fl  = flags + g * 32 * 32;       // 32 slots x 128B per group; flag @+0, id @+64B
  unsigned* cnt = flags + 8 * 32 * 32 + g * 32;   // one counter line (128B) per group

  // Read XCC_ID (hwreg id 20, offset 0, width 4) via builtin — no asm parser.
  const unsigned xcc = __builtin_amdgcn_s_getreg(((4 - 1) << 11) | 20);
  if (tid == 0)
    __hip_atomic_store(fl + s * 32 + 16, xcc + 1u, __ATOMIC_RELAXED, __HIP_MEMORY_SCOPE_AGENT);

  __shared__ float stage[256 * 32];   // 32KB staging for Wh slice (one K-quarter)
  __shared__ float red[4][16][32];    // 8KB cross-wave reduction
  __shared__ unsigned same_sh;

  short8 Bf[8][2][2];                 // [k-chunk][col-tile][hi/lo] -> 128 VGPRs

  // ---- prologue: build Wh B-fragments (hi/lo bf16) ----
  for (int p = 0; p < 4; ++p) {
    for (int it = 0; it < 32; ++it) {
      int kk = it * 8 + (tid >> 5);
      stage[kk * 32 + (tid & 31)] = Wh[(size_t)(p * 256 + kk) * H_ + c0 + (tid & 31)];
    }
    __syncthreads();
    if (wave == p) {
#pragma unroll
      for (int ch = 0; ch < 8; ++ch) {
#pragma unroll
        for (int ct = 0; ct < 2; ++ct) {
          short8 hi, lo;
#pragma unroll
          for (int j = 0; j < 8; ++j) {
            int kk = ch * 32 + ((lane >> 4) * 8) + j;
            float f = stage[kk * 32 + ct * 16 + (lane & 15)];
            unsigned short h16 = f2bf(f);
            hi[j] = (short)h16;
            lo[j] = (short)f2bf(f - bf2f(h16));
          }
          Bf[ch][ct][0] = hi;
          Bf[ch][ct][1] = lo;
        }
      }
    }
    __syncthreads();
  }

  // ---- protocol selection: same-XCD within group AND neighbor group differs ----
  // Spins terminate: all 256 blocks are co-resident (proven by prior passing
  // runs' global flag barrier) and publish their id before any spin.
  if (wave == 0) {
    unsigned idv;
    do {
      idv = __hip_atomic_load(fl + (lane & 31) * 32 + 16,
                              __ATOMIC_RELAXED, __HIP_MEMORY_SCOPE_AGENT);
    } while (__ballot(idv != 0u) != ~0ull);
    const bool uniform = (__ballot(idv == xcc + 1u) == ~0ull);

    unsigned* nfl = flags + ((g + 1) & 7) * 32 * 32;
    unsigned ndv;
    do {
      ndv = __hip_atomic_load(nfl + (lane & 31) * 32 + 16,
                              __ATOMIC_RELAXED, __HIP_MEMORY_SCOPE_AGENT);
    } while (__ballot(ndv != 0u) != ~0ull);
    const bool differs = (__ballot(ndv != xcc + 1u) != 0ull);

    if (lane == 0) same_sh = (uniform && differs) ? 1u : 0u;
  }
  __syncthreads();
  const bool fastp = (same_sh != 0u);

  const int r0    = tid >> 5;                     // 0..7
  const int cc    = tid & 31;
  const int arow  = row0 + (lane & 15);
  const int kbase = wave * 256 + ((lane >> 4) * 8);
  const float bv0 = bias[c0 + cc];                // loop-invariant

  // Yb[0] = bf16(state) for this block's tile
  if (fastp) {
    for (int i = tid; i < 512; i += 256) {
      int r = i >> 5, c = i & 31;
      Yb[(size_t)(row0 + r) * H_ + c0 + c] = f2bf(state[(size_t)(row0 + r) * H_ + c0 + c]);
    }
    run_T_loop<true>(inputs, Wx, Yb, hfinal, fl, cnt, s, wave, lane, Bf, red,
                     r0, cc, arow, kbase, bv0, row0, c0);
  } else {
    for (int i = tid; i < 512; i += 256) {
      int r = i >> 5, c = i & 31;
      st_bf16_agent(Yb + (size_t)(row0 + r) * H_ + c0 + c,
                    f2bf(state[(size_t)(row0 + r) * H_ + c0 + c]));
    }
    run_T_loop<false>(inputs, Wx, Yb, hfinal, fl, cnt, s, wave, lane, Bf, red,
                      r0, cc, arow, kbase, bv0, row0, c0);
  }
}

// ---------- kernel 3: projection GEMM ----------
__global__ __launch_bounds__(256, 2) void proj_gemm(
    const unsigned short* __restrict__ A,   // Yb + B*H
    const unsigned short* __restrict__ Bt,  // [2048][1024] bf16
    const float* __restrict__ bd, float* __restrict__ out)
{
  const int tid = threadIdx.x;
  const int wave = tid >> 6, lane = tid & 63;
  const int wm = wave >> 1, wn = wave & 1;
  const int m0 = blockIdx.y * 128, n0 = blockIdx.x * 128;

  __shared__ unsigned short As[128 * 32];
  __shared__ unsigned short Bs[128 * 32];

  f32x4 acc[4][4];
#pragma unroll
  for (int i = 0; i < 4; ++i)
#pragma unroll
    for (int j = 0; j < 4; ++j)
      acc[i][j] = (f32x4){0.f, 0.f, 0.f, 0.f};

  const int lrow = tid >> 2;
  const int lcol = (tid & 3) * 16;

  for (int k0 = 0; k0 < H_; k0 += 32) {
    __syncthreads();
    async16((const char*)(A  + (size_t)(m0 + lrow)      * H_ + k0) + lcol, (char*)As + tid * 16);
    async16((const char*)(A  + (size_t)(m0 + 64 + lrow) * H_ + k0) + lcol, (char*)As + 4096 + tid * 16);
    async16((const char*)(Bt + (size_t)(n0 + lrow)      * H_ + k0) + lcol, (char*)Bs + tid * 16);
    async16((const char*)(Bt + (size_t)(n0 + 64 + lrow) * H_ + k0) + lcol, (char*)Bs + 4096 + tid * 16);
    __syncthreads();

    short8 af[4], bf[4];
#pragma unroll
    for (int i = 0; i < 4; ++i) {
      af[i] = *(const short8*)(As + (wm * 64 + i * 16 + (lane & 15)) * 32 + (lane >> 4) * 8);
      bf[i] = *(const short8*)(Bs + (wn * 64 + i * 16 + (lane & 15)) * 32 + (lane >> 4) * 8);
    }
#pragma unroll
    for (int i = 0; i < 4; ++i)
#pragma unroll
      for (int j = 0; j < 4; ++j)
        acc[i][j] = __builtin_amdgcn_mfma_f32_16x16x32_bf16(af[i], bf[j], acc[i][j], 0, 0, 0);
  }

#pragma unroll
  for (int i = 0; i < 4; ++i) {
#pragma unroll
    for (int j = 0; j < 4; ++j) {
      int n = n0 + wn * 64 + j * 16 + (lane & 15);
      float bv = bd[n];
#pragma unroll
      for (int r = 0; r < 4; ++r) {
        int m = m0 + wm * 64 + i * 16 + (lane >> 4) * 4 + r;
        out[(size_t)m * V_ + n] = acc[i][j][r] + bv;
      }
    }
  }
}

// ---------- workspace layout ----------
static constexpr size_t YB_BYTES  = (size_t)(T_ + 1) * B_ * H_ * 2;  // 67,371,008
static constexpr size_t WDT_OFF   = YB_BYTES;
static constexpr size_t WDT_BYTES = (size_t)V_ * H_ * 2;             // 4,194,304
static constexpr size_t BAR_OFF   = WDT_OFF + WDT_BYTES;
static constexpr size_t BAR_BYTES = 8 * 32 * 128 + 8 * 128;          // flags/ids + counters

extern "C" void kernel_launch(void* const* d_in, const int* in_sizes, int n_in,
                              void* d_out, int out_size, void* d_ws, size_t ws_size,
                              hipStream_t stream) {
  const int*   inputs = (const int*)d_in[0];
  const float* state  = (const float*)d_in[1];
  const float* Wx     = (const float*)d_in[2];
  const float* Wh     = (const float*)d_in[3];
  const float* b      = (const float*)d_in[4];
  const float* Wd     = (const float*)d_in[5];
  const float* bd     = (const float*)d_in[6];

  float* out    = (float*)d_out;
  float* hfinal = out + (size_t)T_ * B_ * V_;

  unsigned short* Yb    = (unsigned short*)d_ws;
  unsigned short* WdT   = (unsigned short*)((char*)d_ws + WDT_OFF);
  unsigned int*   flags = (unsigned int*)((char*)d_ws + BAR_OFF);

  hipMemsetAsync(flags, 0, BAR_BYTES, stream);   // ws is 0xAA-poisoned each call
  wd_transpose<<<dim3(16, 32), 256, 0, stream>>>(Wd, WdT);
  rnn_recur<<<256, 256, 0, stream>>>(inputs, state, Wx, Wh, b, Yb, hfinal, flags);
  proj_gemm<<<dim3(16, 256), 256, 0, stream>>>(Yb + (size_t)B_ * H_, WdT, bd, out);
}